// Round 10
// baseline (517.814 us; speedup 1.0000x reference)
//
#include <hip/hip_runtime.h>

// Fast HW transcendentals (v_exp_f32 / v_log_f32 / v_rcp_f32), with fallbacks.
#if __has_builtin(__builtin_amdgcn_exp2f)
#define FAST_EXP2(x) __builtin_amdgcn_exp2f(x)
#else
#define FAST_EXP2(x) exp2f(x)
#endif
#if __has_builtin(__builtin_amdgcn_logf)
#define FAST_LOG2(x) __builtin_amdgcn_logf(x)
#else
#define FAST_LOG2(x) log2f(x)
#endif
#if __has_builtin(__builtin_amdgcn_rcpf)
#define FAST_RCP(x) __builtin_amdgcn_rcpf(x)
#else
#define FAST_RCP(x) (1.0f / (x))
#endif

#define LOG2E 1.44269504088896340736f

typedef float v2f __attribute__((ext_vector_type(2)));

__device__ __forceinline__ v2f v2fma(v2f a, v2f b, v2f c) {
    return __builtin_elementwise_fma(a, b, c);
}

// R15: persistent grid + FULLY SCALARIZED body.
// R13/R14 post-mortem: wrapping the unrolled body in a runtime loop makes the
// compiler demote the local arrays (h1[6], h2[6], xs[4], vals[3]) to scratch
// (VGPR_Count=32 << the 64 cap, ~620 B/row scratch round-trip, 1.3 GB HBM,
// 437 us) — straight-line R12 SROA'd the same arrays into registers (30 us).
// Persistent residency itself is proven right: OccupancyPercent 80% vs 9.4%
// in the 7813-short-block churn regime. Fix: remove every indexable local —
// named v2f pairs for h1/h2, four scalars for x, template<int K> for the
// three MLPs (all LDS offsets compile-time). Scratch demotion is then
// impossible regardless of loop-unroll heuristics.
// Per-row op order is verbatim R12 (absmax 1.2207e-4, verified twice).

// tanh on a pair whose input is PRE-SCALED by 2*log2e: tanh = 1 - 2/(exp2(t)+1).
__device__ __forceinline__ v2f fast_tanh2_scaled(v2f t) {
    v2f e;
    e.x = FAST_EXP2(t.x);
    e.y = FAST_EXP2(t.y);
    v2f d = e + (v2f)(1.0f);
    float rp = FAST_RCP(d.x * d.y);
    v2f r;
    r.x = d.y * rp;
    r.y = d.x * rp;
    return v2fma((v2f)(-2.0f), r, (v2f)(1.0f));
}

// sigmoid whose input is PRE-SCALED by -log2e: 1/(1+exp2(t)).
__device__ __forceinline__ float fast_sigmoid_scaled(float t) {
    return FAST_RCP(1.0f + FAST_EXP2(t));
}

// One tiny MLP (k = K), LDS offsets all compile-time. Returns the pre-sigmoid
// output y in the -log2e-scaled domain. No arrays, no runtime indexing.
template <int K>
__device__ __forceinline__ float mlp_eval(const float* __restrict__ w,
                                          float x0, float x1, float x2, float x3) {
    // ---- layer 1: 3 pair-groups -> h1 pairs (a,b,c) ----
    v2f h1a, h1b, h1c;
#define L1_GROUP(JP, OUT)                                                     \
    {                                                                         \
        const float* ga = w + (K * 3 + (JP)) * 12;                            \
        float4 wa = *(const float4*)(ga);                                     \
        float4 wb = *(const float4*)(ga + 4);                                 \
        v2f acc = *(const v2f*)(ga + 8);                                      \
        acc = v2fma((v2f)(x0), (v2f){wa.x, wa.y}, acc);                       \
        acc = v2fma((v2f)(x1), (v2f){wa.z, wa.w}, acc);                       \
        acc = v2fma((v2f)(x2), (v2f){wb.x, wb.y}, acc);                       \
        acc = v2fma((v2f)(x3), (v2f){wb.z, wb.w}, acc);                       \
        OUT = fast_tanh2_scaled(acc);                                         \
    }
    L1_GROUP(0, h1a)
    L1_GROUP(1, h1b)
    L1_GROUP(2, h1c)
#undef L1_GROUP

    // ---- layer 2: 3 pair-groups -> h2 pairs (a,b,c) ----
    v2f h2a, h2b, h2c;
#define L2_GROUP(JP, OUT)                                                     \
    {                                                                         \
        const float* gb = w + 108 + (K * 3 + (JP)) * 16;                      \
        float4 w0 = *(const float4*)(gb);                                     \
        float4 w1 = *(const float4*)(gb + 4);                                 \
        float4 w2 = *(const float4*)(gb + 8);                                 \
        v2f acc = *(const v2f*)(gb + 12);                                     \
        acc = v2fma((v2f)(h1a.x), (v2f){w0.x, w0.y}, acc);                    \
        acc = v2fma((v2f)(h1a.y), (v2f){w0.z, w0.w}, acc);                    \
        acc = v2fma((v2f)(h1b.x), (v2f){w1.x, w1.y}, acc);                    \
        acc = v2fma((v2f)(h1b.y), (v2f){w1.z, w1.w}, acc);                    \
        acc = v2fma((v2f)(h1c.x), (v2f){w2.x, w2.y}, acc);                    \
        acc = v2fma((v2f)(h1c.y), (v2f){w2.z, w2.w}, acc);                    \
        OUT = fast_tanh2_scaled(acc);                                         \
    }
    L2_GROUP(0, h2a)
    L2_GROUP(1, h2b)
    L2_GROUP(2, h2c)
#undef L2_GROUP

    // ---- layer 3 (scaled domain), scalar sequential order ----
    const float* gc = w + 252 + K * 8;
    float4 c0 = *(const float4*)(gc);   // W3'[0..3]
    v2f c45 = *(const v2f*)(gc + 4);    // W3'[4..5]
    float y = gc[6];                    // b3'
    y = fmaf(h2a.x, c0.x, y);
    y = fmaf(h2a.y, c0.y, y);
    y = fmaf(h2b.x, c0.z, y);
    y = fmaf(h2b.y, c0.w, y);
    y = fmaf(h2c.x, c45.x, y);
    y = fmaf(h2c.y, c45.y, y);
    return y;
}

constexpr int BLOCK = 256;

__global__ __launch_bounds__(256, 8) void subsurf_kernel(
    const float* __restrict__ x, const float* __restrict__ S1,
    const float* __restrict__ W1, const float* __restrict__ b1,
    const float* __restrict__ W2, const float* __restrict__ b2,
    const float* __restrict__ W3, const float* __restrict__ b3,
    float* __restrict__ out, int n)
{
    // LDS layout (R12's pre-scaled b128-bundled layout):
    //   A (L1): 9 groups x 12 floats @0:   [8x W1' pairs][2x b1'][2 pad] (48B)
    //   B (L2): 9 groups x 16 floats @108: [12x W2' pairs][2x b2'][2 pad] (64B)
    //   C (L3): 3 groups x  8 floats @252: [6x W3'][b3'][pad] (32B)
    __shared__ __align__(16) float w[280];
    int t = threadIdx.x;

    const float SC_H = 2.0f * LOG2E;   // hidden-layer fold (tanh input scale)
    const float SC_O = -LOG2E;         // output-layer fold (sigmoid input scale)
    if (t < 252) {
        if (t < 108) {
            int g = t / 12, r = t % 12;
            int k = g / 3, jp = g % 3;
            float v = 0.0f;
            if (r < 8)       v = SC_H * W1[k * 24 + (r >> 1) * 6 + 2 * jp + (r & 1)];
            else if (r < 10) v = SC_H * b1[k * 6 + 2 * jp + (r - 8)];
            w[t] = v;
        } else {
            int u = t - 108;
            int g = u / 16, r = u % 16;
            int k = g / 3, jp = g % 3;
            float v = 0.0f;
            if (r < 12)      v = SC_H * W2[k * 36 + (r >> 1) * 6 + 2 * jp + (r & 1)];
            else if (r < 14) v = SC_H * b2[k * 6 + 2 * jp + (r - 12)];
            w[t] = v;
        }
    }
    if (t < 24) {
        int k = t / 8, r = t % 8;
        float v = 0.0f;
        if (r < 6)       v = SC_O * W3[k * 6 + r];
        else if (r == 6) v = SC_O * b3[k];
        w[252 + t] = v;
    }
    __syncthreads();

    const int chunks = (n + BLOCK - 1) / BLOCK;
    for (int c = blockIdx.x; c < chunks; c += gridDim.x) {
        int i = c * BLOCK + t;
        int ic = min(i, n - 1);   // clamp: always-in-bounds load; store guarded
        float4 xv = ((const float4*)x)[ic];
        float s1 = S1[ic];

        float y0 = mlp_eval<0>(w, xv.x, xv.y, xv.z, xv.w);
        float y1 = mlp_eval<1>(w, xv.x, xv.y, xv.z, xv.w);
        float y2 = mlp_eval<2>(w, xv.x, xv.y, xv.z, xv.w);

        // Bit-match numpy f32 constant arithmetic for lows / (highs - lows).
        float S1max = fmaf(500.0f - 100.0f, fast_sigmoid_scaled(y0), 100.0f);
        float ks    = fmaf(100.0f - 0.01f,  fast_sigmoid_scaled(y1), 0.01f);
        float nexp  = fmaf(10.0f - 0.01f,   fast_sigmoid_scaled(y2), 0.01f);

        // (S1/S1max)^n in log2 domain: handles S1==0 (log2->-inf, exp2->0).
        float lr = FAST_LOG2(s1) - FAST_LOG2(S1max);
        float flow = ks * FAST_EXP2(nexp * lr);
        flow = fminf(fmaxf(flow, 0.0f), S1max);
        if (i < n) out[i] = flow;
    }
}

extern "C" void kernel_launch(void* const* d_in, const int* in_sizes, int n_in,
                              void* d_out, int out_size, void* d_ws, size_t ws_size,
                              hipStream_t stream) {
    const float* x  = (const float*)d_in[0];
    const float* S1 = (const float*)d_in[1];
    const float* W1 = (const float*)d_in[2];
    const float* b1 = (const float*)d_in[3];
    const float* W2 = (const float*)d_in[4];
    const float* b2 = (const float*)d_in[5];
    const float* W3 = (const float*)d_in[6];
    const float* b3 = (const float*)d_in[7];
    float* out = (float*)d_out;

    int n = out_size;  // N = 2,000,000 rows, one output per row
    int chunks = (n + BLOCK - 1) / BLOCK;
    int grid = chunks < 2048 ? chunks : 2048;  // 8 blocks/CU x 256 CUs, persistent
    subsurf_kernel<<<grid, BLOCK, 0, stream>>>(x, S1, W1, b1, W2, b2, W3, b3, out, n);
}